// Round 4
// baseline (284.106 us; speedup 1.0000x reference)
//
#include <hip/hip_runtime.h>
#include <cstdint>
#include <cstddef>

// ---------------------------------------------------------------------------
// SpatialGRU 32x32, B=64, U=64, C=64. Persistent: 32 rows x 4 batch-tiles.
// R10: SPLIT HANDOFF. h = zpart + eiinv*th. Producer stores the three f16
// pieces as separate self-validating dwords: zp/ei right after s2 (early,
// off-chain, waves 0..3) and th ~100cy after the last GEMM2 MFMA (waves
// 4..7). Consumer polls its 3 own dwords (detect gated by th) and
// reconstructs h with 2 VALU. Eliminates s3 + [F]: 3 barriers/iter; the
// producer-side softmax needed for its own rotation runs on waves 4..7
// AFTER the th store (off-chain, self-contained: reads only pre-s2 data).
//  - GEMM2 n-split (waves 4..7: 16 out-cols, full K=256, 8 MFMA) as R9.
//  - parity double-buffered qs32 hL/hD and qf x-slot as R9.
//  - keeps R8's poll-overlapped GEMM1 split + XCD-affinity swizzle.
//  - hbuf stride 1536 dw/slot (th|zp|ei) = 24 MB; if ws_size < 24 MB,
//    fallback mode (SPLIT=0): single h-dword handoff, extra barrier, 8 MB.
// Validity: every stored halfword has LSB|=1; harness ws poison 0xAA gives
// 0xAAAA halfwords (LSB=0) -> can never satisfy the check.
// ---------------------------------------------------------------------------

#define LDIM   32
#define NBT    4
#define BT     16
#define TPB    512
#define UNITS  64

typedef _Float16 f16;
typedef _Float16 f16x8 __attribute__((ext_vector_type(8)));
typedef float    f32x4 __attribute__((ext_vector_type(4)));

__global__ __launch_bounds__(TPB, 2) void spatial_gru_kernel(
    const float* __restrict__ x,     // (B, C, 32, 32)
    const float* __restrict__ W,     // (256, 448)
    const float* __restrict__ Urec,  // (192, 64)
    const float* __restrict__ bias,  // (512,)
    const float* __restrict__ Wij,   // (64, 64)
    float* __restrict__ out,         // (B, U)
    uint32_t* __restrict__ hbuf,     // slots of STR dwords: [th | zp | ei]
    const int SPLIT)
{
    // XCD-affinity swizzle: physical block p -> XCD p%8; 4 consecutive rows
    // per XCD so most vertical handoffs stay on-die. Bijective on [0,128).
    const int p    = blockIdx.x;
    const int xcd  = p & 7;
    const int slot = p >> 3;         // 0..15
    const int row  = xcd * 4 + (slot >> 2);
    const int bt   = slot & 3;
    const int b0   = bt * BT;
    const int t    = (int)threadIdx.x;
    const int u    = t & 63;
    const int g    = t >> 6;         // wave id 0..7
    const int l15  = t & 15;         // MFMA n-col / A-row lane
    const int lq   = (t & 63) >> 4;  // MFMA k-quad
    const int STR  = SPLIT ? 1536 : 512;

    // ---- LDS ----
    // qf  : GEMM1 A (f16) [b][k]: 0:64 hT | 64:128 hL | 128:192 hD |
    //       192:256 s(par0) | 256:320 s(par1)
    // rf  : GEMM2 A (f16) [b][0:192] = r*{hL,hT,hD}
    // qs32: fp32 state [b][c]: 0:64 hT | 64:128 hL0 | 128:192 hD0 |
    //       192:256 hL1 | 256:320 hD1   (hL/hD parity by j&1)
    // Gsz : z logits fp32 [b][0:256]; fallback mode only: [b][u]=zp,
    //       [b][64+u]=ei after the waves-0..3 softmax
    __shared__ __attribute__((aligned(16))) f16 qf[BT][328];
    __shared__ __attribute__((aligned(16))) f16 rf[BT][200];
    __shared__ float qs32[BT][324];
    __shared__ float Gsz [BT][260];

    // ---- GEMM1 weights resident (waves 0..6: 64 cols each) ----
    f16x8 wreg[4][8];
    float bias1[4] = {0.f, 0.f, 0.f, 0.f};
    if (g < 7) {
        const int nb = g * 64 + l15;
#pragma unroll
        for (int T = 0; T < 4; ++T) {
            bias1[T] = bias[nb + 16 * T];
#pragma unroll
            for (int s = 0; s < 8; ++s) {
                f16x8 v;
#pragma unroll
                for (int jj = 0; jj < 8; ++jj) {
                    int kk = s * 32 + lq * 8 + jj;
                    v[jj] = (f16)W[(size_t)kk * 448 + nb + 16 * T];
                }
                wreg[T][s] = v;
            }
        }
    }
    // ---- GEMM2 weights: waves 4..7 hold FULL K=256 for 16 n-cols each ----
    f16x8 wreg2[8];
    float bijE = 0.f;
    if (g >= 4) {
        const int nn = (g - 4) * 16 + l15;
        bijE = bias[448 + nn];
#pragma unroll
        for (int s = 0; s < 8; ++s) {
            f16x8 v;
#pragma unroll
            for (int jj = 0; jj < 8; ++jj) {
                int kk = s * 32 + lq * 8 + jj;
                float wv = (kk < 192) ? Urec[kk * 64 + nn] : Wij[(kk - 192) * 64 + nn];
                v[jj] = (f16)wv;
            }
            wreg2[s] = v;
        }
    }

    // ---- zero init: all qs32 state, qf hT/hL/hD (0:192) ----
    for (int idx = t; idx < BT * 324; idx += TPB)
        ((float*)qs32)[idx] = 0.f;
    for (int idx = t; idx < 192 * BT; idx += TPB) {
        int b = idx & 15, k = idx >> 4;
        qf[b][k] = (f16)0.f;
    }

    // x: this thread handles channel u, batches b0+g and b0+g+8
    const size_t xb0 = (size_t)(b0 + g) * 65536 + (size_t)u * 1024 + (size_t)row * 32;
    const size_t xb1 = xb0 + (size_t)8 * 65536;
    {   // stage x(j=0) into parity-0 s slot
        float x0 = x[xb0], x1 = x[xb1];
        qf[g][192 + u]     = (f16)x0;
        qf[g + 8][192 + u] = (f16)x1;
    }

    for (int j = 0; j < LDIM; ++j) {
        const int par  = j & 1;
        const int scur = 192 + par * 64;
        const int snxt = 192 + (par ^ 1) * 64;
        const int hlc  = 64 + par * 128, hdc = 128 + par * 128;
        const int hln  = 64 + (par ^ 1) * 128, hdn = 128 + (par ^ 1) * 128;

        __syncthreads();   // s1 — prev-tail writes (h, rotations, x) visible

        // ---- [A] issue own-dword poll loads (fly during [C-pre]) ----
        uint32_t wT = 0, wZ = 0, wE = 0;
        const uint32_t* sp = hbuf;
        if (row > 0) {
            sp = hbuf + (size_t)(((row - 1) * LDIM + j) * NBT + bt) * STR + (g << 6) + u;
            wT = __hip_atomic_load(sp, __ATOMIC_RELAXED, __HIP_MEMORY_SCOPE_AGENT);
            if (SPLIT) {
                wZ = __hip_atomic_load(sp + 512,  __ATOMIC_RELAXED, __HIP_MEMORY_SCOPE_AGENT);
                wE = __hip_atomic_load(sp + 1024, __ATOMIC_RELAXED, __HIP_MEMORY_SCOPE_AGENT);
            }
        }
        float nx0 = 0.f, nx1 = 0.f;
        if (j < LDIM - 1) { nx0 = x[xb0 + j + 1]; nx1 = x[xb1 + j + 1]; }

        // ---- [C-pre] GEMM1 k=64:256 (waves 0..6; hL/hD/s all local) ----
        f32x4 acc[4];
        if (g < 7) {
#pragma unroll
            for (int T = 0; T < 4; ++T)
                acc[T] = (f32x4){bias1[T], bias1[T], bias1[T], bias1[T]};
#pragma unroll
            for (int s = 2; s < 8; ++s) {
                const f16* ap = (s < 6) ? &qf[l15][s * 32 + lq * 8]
                                        : &qf[l15][scur + (s - 6) * 32 + lq * 8];
                f16x8 a = *(const f16x8*)ap;
#pragma unroll
                for (int T = 0; T < 4; ++T)
                    acc[T] = __builtin_amdgcn_mfma_f32_16x16x32_f16(a, wreg[T][s], acc[T], 0, 0, 0);
            }
        }

        // ---- [A'] complete poll; reconstruct h; stage hT (own slots) ----
        {
            float ht0 = 0.f, ht1 = 0.f;
            f16 hf0 = (f16)0.f, hf1 = (f16)0.f;
            if (row > 0) {
                if (SPLIT) {
                    while (((wT & wZ & wE) & 0x00010001u) != 0x00010001u) {
                        __builtin_amdgcn_s_sleep(1);
                        wT = __hip_atomic_load(sp,        __ATOMIC_RELAXED, __HIP_MEMORY_SCOPE_AGENT);
                        wZ = __hip_atomic_load(sp + 512,  __ATOMIC_RELAXED, __HIP_MEMORY_SCOPE_AGENT);
                        wE = __hip_atomic_load(sp + 1024, __ATOMIC_RELAXED, __HIP_MEMORY_SCOPE_AGENT);
                    }
                    f16 th0 = __builtin_bit_cast(f16, (uint16_t)(wT & 0xFFFFu));
                    f16 th1 = __builtin_bit_cast(f16, (uint16_t)(wT >> 16));
                    f16 zp0 = __builtin_bit_cast(f16, (uint16_t)(wZ & 0xFFFFu));
                    f16 zp1 = __builtin_bit_cast(f16, (uint16_t)(wZ >> 16));
                    f16 ei0 = __builtin_bit_cast(f16, (uint16_t)(wE & 0xFFFFu));
                    f16 ei1 = __builtin_bit_cast(f16, (uint16_t)(wE >> 16));
                    ht0 = (float)zp0 + (float)ei0 * (float)th0;
                    ht1 = (float)zp1 + (float)ei1 * (float)th1;
                    hf0 = (f16)ht0;
                    hf1 = (f16)ht1;
                } else {
                    while ((wT & 0x00010001u) != 0x00010001u) {
                        __builtin_amdgcn_s_sleep(1);
                        wT = __hip_atomic_load(sp, __ATOMIC_RELAXED, __HIP_MEMORY_SCOPE_AGENT);
                    }
                    hf0 = __builtin_bit_cast(f16, (uint16_t)(wT & 0xFFFFu));
                    hf1 = __builtin_bit_cast(f16, (uint16_t)(wT >> 16));
                    ht0 = (float)hf0;
                    ht1 = (float)hf1;
                }
            }
            qs32[g][u]     = ht0;  qf[g][u]     = hf0;
            qs32[g + 8][u] = ht1;  qf[g + 8][u] = hf1;
        }
        __syncthreads();   // s1b — hT staged visible

        // ---- [C-post] GEMM1 k=0:64 (waves 0..6) + sigmoid/z dumps ----
        if (g < 7) {
            {
                f16x8 a0 = *(const f16x8*)&qf[l15][lq * 8];
                f16x8 a1 = *(const f16x8*)&qf[l15][32 + lq * 8];
#pragma unroll
                for (int T = 0; T < 4; ++T)
                    acc[T] = __builtin_amdgcn_mfma_f32_16x16x32_f16(a0, wreg[T][0], acc[T], 0, 0, 0);
#pragma unroll
                for (int T = 0; T < 4; ++T)
                    acc[T] = __builtin_amdgcn_mfma_f32_16x16x32_f16(a1, wreg[T][1], acc[T], 0, 0, 0);
            }
            if (g < 3) {
                // g=0: r*hL ; g=1: r*hT ; g=2: r*hD   (parity-cur states)
                const int colbase = (g == 0) ? hlc : (g == 1) ? 0 : hdc;
#pragma unroll
                for (int T = 0; T < 4; ++T)
#pragma unroll
                    for (int r = 0; r < 4; ++r) {
                        float rr = 1.f / (1.f + __expf(-acc[T][r]));
                        int b = lq * 4 + r;
                        float hv = qs32[b][colbase + T * 16 + l15];
                        rf[b][g * 64 + T * 16 + l15] = (f16)(rr * hv);
                    }
            } else {
                const int zb = (g - 3) * 64;
#pragma unroll
                for (int T = 0; T < 4; ++T)
#pragma unroll
                    for (int r = 0; r < 4; ++r)
                        Gsz[lq * 4 + r][zb + T * 16 + l15] = acc[T][r];
            }
        }
        __syncthreads();   // s2 — rf + Gsz + (parity-cur states) stable

        // ---- [E'] barrier-free tail span ----
        const size_t curbase = (size_t)((row * LDIM + j) * NBT + bt) * STR;
        uint16_t* hp16 = (uint16_t*)(hbuf + curbase);
        float thv[4] = {0.f, 0.f, 0.f, 0.f};

        if (g >= 4) {
            // full-K GEMM2 (8 MFMA, 2 interleaved acc chains)
            f32x4 aA = (f32x4){0.f, 0.f, 0.f, 0.f};
            f32x4 aB = (f32x4){0.f, 0.f, 0.f, 0.f};
#pragma unroll
            for (int s = 0; s < 8; s += 2) {
                const f16* apA = (s < 6) ? &rf[l15][s * 32 + lq * 8]
                                         : &qf[l15][scur + (s - 6) * 32 + lq * 8];
                f16x8 a = *(const f16x8*)apA;
                aA = __builtin_amdgcn_mfma_f32_16x16x32_f16(a, wreg2[s], aA, 0, 0, 0);
                const f16* apB = (s + 1 < 6) ? &rf[l15][(s + 1) * 32 + lq * 8]
                                             : &qf[l15][scur + (s + 1 - 6) * 32 + lq * 8];
                f16x8 b_ = *(const f16x8*)apB;
                aB = __builtin_amdgcn_mfma_f32_16x16x32_f16(b_, wreg2[s + 1], aB, 0, 0, 0);
            }
            const int n = (g - 4) * 16 + l15;
            // th: compute + (split) store IMMEDIATELY — this gates row+1
#pragma unroll
            for (int rr = 0; rr < 4; ++rr) {
                const int b = lq * 4 + rr;
                float hh = bijE + aA[rr] + aB[rr];
                float e2 = __expf(2.f * hh);
                thv[rr] = 1.f - 2.f / (e2 + 1.f);        // tanh
                if (SPLIT) {
                    uint16_t th16 = (uint16_t)(__builtin_bit_cast(uint16_t, (f16)thv[rr]) | 1u);
                    __hip_atomic_store(hp16 + ((((b & 7) << 6) + n) << 1) + (b >> 3),
                                       th16, __ATOMIC_RELAXED, __HIP_MEMORY_SCOPE_AGENT);
                }
            }
            if (SPLIT) {
                // OFF-CHAIN: own softmax (pre-s2 data only) -> local h for
                // rotation + out. Duplicated with waves 0..3 by design.
#pragma unroll
                for (int rr = 0; rr < 4; ++rr) {
                    const int b = lq * 4 + rr;
                    float zi = Gsz[b][n],       zl = Gsz[b][64 + n];
                    float zt = Gsz[b][128 + n], zd = Gsz[b][192 + n];
                    float hT = qs32[b][n], hL = qs32[b][hlc + n], hD = qs32[b][hdc + n];
                    float mx = fmaxf(fmaxf(zi, zl), fmaxf(zt, zd));
                    float ei = __expf(zi - mx), el = __expf(zl - mx);
                    float et = __expf(zt - mx), ed = __expf(zd - mx);
                    float inv = 1.f / (ei + el + et + ed);
                    float h = (el * hL + et * hT + ed * hD + ei * thv[rr]) * inv;
                    qs32[b][hln + n] = h;          // rotation hL(next) <- h
                    qf[b][64 + n]    = (f16)h;
                    if (row == LDIM - 1 && j == LDIM - 1)
                        out[(size_t)(b0 + b) * UNITS + n] = h;
                }
            }
        } else {
            // waves 0..3: softmax partials; split -> straight to hbuf;
            // fallback -> Gsz in place. Plus hD<-hT parity rotation.
#pragma unroll
            for (int i = 0; i < 4; ++i) {
                const int b = g * 4 + i;
                float zi = Gsz[b][u],       zl = Gsz[b][64 + u];
                float zt = Gsz[b][128 + u], zd = Gsz[b][192 + u];
                float hT = qs32[b][u], hL = qs32[b][hlc + u], hD = qs32[b][hdc + u];
                float mx = fmaxf(fmaxf(zi, zl), fmaxf(zt, zd));
                float ei = __expf(zi - mx), el = __expf(zl - mx);
                float et = __expf(zt - mx), ed = __expf(zd - mx);
                float inv = 1.f / (ei + el + et + ed);
                float zp  = (el * hL + et * hT + ed * hD) * inv;
                float eiv = ei * inv;
                if (SPLIT) {
                    uint16_t zp16 = (uint16_t)(__builtin_bit_cast(uint16_t, (f16)zp)  | 1u);
                    uint16_t ei16 = (uint16_t)(__builtin_bit_cast(uint16_t, (f16)eiv) | 1u);
                    const int dw = ((b & 7) << 6) + u;
                    __hip_atomic_store(hp16 + ((512  + dw) << 1) + (b >> 3),
                                       zp16, __ATOMIC_RELAXED, __HIP_MEMORY_SCOPE_AGENT);
                    __hip_atomic_store(hp16 + ((1024 + dw) << 1) + (b >> 3),
                                       ei16, __ATOMIC_RELAXED, __HIP_MEMORY_SCOPE_AGENT);
                } else {
                    Gsz[b][u]      = zp;
                    Gsz[b][64 + u] = eiv;
                }
                // rotation: hD(next parity) <- hT(cur)
                qs32[b][hdn + u] = hT;
                qf[b][128 + u]   = qf[b][u];
            }
        }
        // stage next x into parity-next s slot (thread-own; read next iter)
        qf[g][snxt + u]     = (f16)nx0;
        qf[g + 8][snxt + u] = (f16)nx1;

        if (!SPLIT) {
            __syncthreads();   // sF — zp/ei in Gsz visible (fallback only)
            if (g >= 4) {
                const int n = (g - 4) * 16 + l15;
#pragma unroll
                for (int rr = 0; rr < 4; ++rr) {
                    const int b = lq * 4 + rr;
                    float h = Gsz[b][n] + Gsz[b][64 + n] * thv[rr];
                    uint16_t h16 = (uint16_t)(__builtin_bit_cast(uint16_t, (f16)h) | 1u);
                    __hip_atomic_store(hp16 + ((((b & 7) << 6) + n) << 1) + (b >> 3),
                                       h16, __ATOMIC_RELAXED, __HIP_MEMORY_SCOPE_AGENT);
                    qs32[b][hln + n] = h;
                    qf[b][64 + n]    = (f16)h;
                    if (row == LDIM - 1 && j == LDIM - 1)
                        out[(size_t)(b0 + b) * UNITS + n] = h;
                }
            }
        }
        // next s1 covers cross-wave visibility of all tail writes
    }
}

extern "C" void kernel_launch(void* const* d_in, const int* in_sizes, int n_in,
                              void* d_out, int out_size, void* d_ws, size_t ws_size,
                              hipStream_t stream) {
    const float* x    = (const float*)d_in[0];
    const float* W    = (const float*)d_in[1];
    const float* Urec = (const float*)d_in[2];
    const float* bias = (const float*)d_in[3];
    const float* Wij  = (const float*)d_in[4];
    float* out = (float*)d_out;

    // Split handoff needs 32*32*4 slots x 1536 dwords = 24 MB of workspace.
    // Harness re-poisons ws with 0xAA each launch; 0xAAAA halfwords always
    // fail the LSB validity test in either mode.
    const size_t need = (size_t)LDIM * LDIM * NBT * 1536 * 4;
    const int split = (ws_size >= need) ? 1 : 0;
    uint32_t* hbuf = (uint32_t*)d_ws;

    spatial_gru_kernel<<<LDIM * NBT, TPB, 0, stream>>>(
        x, W, Urec, bias, Wij, out, hbuf, split);
}